// Round 5
// baseline (115.977 us; speedup 1.0000x reference)
//
#include <hip/hip_runtime.h>

// PastFutureContext: B=8, N=1024, d=h=512 — bf16 MFMA, ring-3 LDS + counted vmcnt (T3/T4)
// + bank-conflict-free LDS via pre-swizzled global source (T2, rule #21).
// Math: out = sp_i*(trilW @ GaT^T) + sf_i*(triuW @ GcT^T) + Gb, where
//   W[b]    = proj[b] @ F[b]^T        (proj = F@W1^T + b1)
//   GacT[b] = [W2a;W2c] @ F[b]^T * sm_j
//   Gb      = F @ W2b^T + b2   — written straight into out (f32); tri does RMW.
// K-loop: stage tile k+2 -> ring slot; compute tile k; s_waitcnt vmcnt(4) (tile k+1
// ready, k+2's loads stay in flight ACROSS the raw s_barrier). Never vmcnt(0) mid-loop.

constexpr int BATCH = 8;
constexpr int SEQ   = 1024;
constexpr int DIM   = 512;
constexpr int HID   = 512;

typedef __bf16 bf16_t;
typedef bf16_t bf16x8 __attribute__((ext_vector_type(8)));
typedef float  f32x4  __attribute__((ext_vector_type(4)));
typedef float  f4     __attribute__((ext_vector_type(4)));

typedef __attribute__((address_space(1))) void gv_t;
typedef __attribute__((address_space(3))) void lv_t;

__device__ __forceinline__ void gload16(const bf16_t* g, bf16_t* l) {
  __builtin_amdgcn_global_load_lds((gv_t*)g, (lv_t*)l, 16, 0, 0);
}

#define WAITCNT4() asm volatile("s_waitcnt vmcnt(4)" ::: "memory")
#define WAITCNT0() asm volatile("s_waitcnt vmcnt(0)" ::: "memory")
#define BAR()      { __builtin_amdgcn_s_barrier(); __builtin_amdgcn_sched_barrier(0); }

// Stage a [ROWS x 32] bf16 tile (row-major, ld elems) into LDS, 16-row blocks of
// 512 elems. Lane l lands at elem l*8 of its block (HW: base + 16B*l, linear).
// SWIZZLE: lane l fetches col-slot ((l&3)-(l>>3))&3 so that read-side slot
// q(r,c) = (r<<2)|((c+(r>>1))&3) holds (row r, slot c). Spreads a 16-lane
// fragment read over 8 bank-groups (2-way, free) instead of 2 (8-way).
template <int ROWS>
__device__ __forceinline__ void stage(const bf16_t* g, int ld, bf16_t* lds,
                                      int w, int lane) {
  const int r0 = lane >> 2;
  const int kc = ((((lane & 3) - (lane >> 3)) & 3)) * 8;
#pragma unroll
  for (int i = 0; i < ROWS / 64; ++i) {
    const int s = w * (ROWS / 64) + i;
    gload16(g + (size_t)(s * 16 + r0) * ld + kc, lds + s * 512);
  }
}

// read-side swizzled elem offset within a 16-row block, for row-in-block fr, slot c0
__device__ __forceinline__ int swz8(int fr, int c0) {
  return (((fr << 2) | ((c0 + (fr >> 1)) & 3)) << 3);
}

// ---- S0: parallel scales ----------------------------------------------------
__global__ __launch_bounds__(1024) void scales_kernel(
    const int* __restrict__ smask, float* __restrict__ sp, float* __restrict__ sf) {
  const int b = blockIdx.x, t = threadIdx.x;
  const int v = smask[b * SEQ + t];
  int x = v;
#pragma unroll
  for (int o = 1; o < 64; o <<= 1) {
    int y = __shfl_up(x, o, 64);
    if ((t & 63) >= o) x += y;
  }
  __shared__ int wsum[16], wpre[17];
  if ((t & 63) == 63) wsum[t >> 6] = x;
  __syncthreads();
  if (t == 0) { int c = 0; for (int w = 0; w < 16; ++w) { wpre[w] = c; c += wsum[w]; } wpre[16] = c; }
  __syncthreads();
  const int inc = x + wpre[t >> 6];
  const float P  = (float)(inc - v);
  const float Fu = (float)(wpre[16] - inc);
  sp[b * SEQ + t] = v ? 1.f / (P  + 1e-8f) : 0.f;
  sf[b * SEQ + t] = v ? 1.f / (Fu + 1e-8f) : 0.f;
}

// ---- S1a: F -> bf16 ----------------------------------------------------------
__global__ void cvt_kernel(const float* __restrict__ in, bf16_t* __restrict__ out, int n8) {
  const int i = blockIdx.x * blockDim.x + threadIdx.x;
  if (i >= n8) return;
  const f4* p = (const f4*)(in + (size_t)i * 8);
  f4 v0 = p[0], v1 = p[1];
  bf16x8 o;
  o[0] = (bf16_t)v0[0]; o[1] = (bf16_t)v0[1]; o[2] = (bf16_t)v0[2]; o[3] = (bf16_t)v0[3];
  o[4] = (bf16_t)v1[0]; o[5] = (bf16_t)v1[1]; o[6] = (bf16_t)v1[2]; o[7] = (bf16_t)v1[3];
  *(bf16x8*)(out + (size_t)i * 8) = o;
}

// ---- S1b: weights -> bf16, restacked ----------------------------------------
__global__ __launch_bounds__(256) void prepw_kernel(
    const float* __restrict__ W1, const float* __restrict__ W2,
    bf16_t* __restrict__ Wpg, bf16_t* __restrict__ W2ac) {
  const int idx = blockIdx.x * 256 + threadIdx.x;
  const int r = idx >> 6, c8 = (idx & 63) * 8;
  const float* src;
  bf16_t* dst;
  if (r < 512)        { src = W1 + (size_t)r * 512 + c8;                    dst = Wpg  + (size_t)r * 512 + c8; }
  else if (r < 1024)  { src = W2 + (size_t)(r - 512) * 1536 + 512 + c8;     dst = Wpg  + (size_t)r * 512 + c8; }
  else if (r < 1536)  { src = W2 + (size_t)(r - 1024) * 1536 + c8;          dst = W2ac + (size_t)(r - 1024) * 512 + c8; }
  else                { src = W2 + (size_t)(r - 1536) * 1536 + 1024 + c8;   dst = W2ac + (size_t)(r - 1024) * 512 + c8; }
  f4 v0 = *(const f4*)src, v1 = *(const f4*)(src + 4);
  bf16x8 o;
  o[0] = (bf16_t)v0[0]; o[1] = (bf16_t)v0[1]; o[2] = (bf16_t)v0[2]; o[3] = (bf16_t)v0[3];
  o[4] = (bf16_t)v1[0]; o[5] = (bf16_t)v1[1]; o[6] = (bf16_t)v1[2]; o[7] = (bf16_t)v1[3];
  *(bf16x8*)dst = o;
}

// ---- ring-3 counted-vmcnt 128x128 GEMM core ----------------------------------
// As/Bs: ring bases, 3 buffers of 4096 elems (128x32) each.
__device__ __forceinline__ void gemm_ring(
    const bf16_t* __restrict__ A, int lda, const bf16_t* __restrict__ Bt, int ldb,
    int K, bf16_t* As, bf16_t* Bs, f32x4 acc[4][4],
    int w, int lane, int qoff, int mw, int nw) {
  const int NT = K / 32;
  stage<128>(A,       lda, As,        w, lane);
  stage<128>(Bt,      ldb, Bs,        w, lane);
  stage<128>(A + 32,  lda, As + 4096, w, lane);
  stage<128>(Bt + 32, ldb, Bs + 4096, w, lane);
  WAITCNT4();
  BAR();
  int cur = 0;
  for (int k = 0; k < NT; ++k) {
    if (k + 2 < NT) {
      const int nx = (cur >= 1) ? cur - 1 : 2;          // (cur+2)%3
      stage<128>(A  + (k + 2) * 32, lda, As + nx * 4096, w, lane);
      stage<128>(Bt + (k + 2) * 32, ldb, Bs + nx * 4096, w, lane);
    }
    const bf16_t* ab = As + cur * 4096 + (mw >> 4) * 512 + qoff;
    const bf16_t* bb = Bs + cur * 4096 + (nw >> 4) * 512 + qoff;
    bf16x8 a[4], b[4];
#pragma unroll
    for (int s = 0; s < 4; ++s) a[s] = *(const bf16x8*)&ab[s * 512];
#pragma unroll
    for (int t = 0; t < 4; ++t) b[t] = *(const bf16x8*)&bb[t * 512];
#pragma unroll
    for (int s = 0; s < 4; ++s)
#pragma unroll
      for (int t = 0; t < 4; ++t)
        acc[s][t] = __builtin_amdgcn_mfma_f32_16x16x32_bf16(a[s], b[t], acc[s][t], 0, 0, 0);
    if (k + 1 < NT) {
      if (k + 2 < NT) { WAITCNT4(); } else { WAITCNT0(); }
      BAR();
    }
    cur = (cur == 2) ? 0 : cur + 1;
  }
}

#define TILE_IDS                                  \
  const int tid = threadIdx.x;                    \
  const int w = tid >> 6, lane = tid & 63;        \
  const int fr = lane & 15;                       \
  const int qoff = swz8(fr, lane >> 4);           \
  const int mw = (w >> 1) * 64, nw = (w & 1) * 64;\
  const int cr = (lane >> 4) * 4, cc = lane & 15;

// ---- S2: [proj | Gb] = F @ [W1;W2b]^T + [b1;b2]; Gb straight into out --------
__global__ __launch_bounds__(256) void pg_mfma(
    const bf16_t* __restrict__ Fbf, const bf16_t* __restrict__ Wpg,
    const float* __restrict__ b1, const float* __restrict__ b2,
    bf16_t* __restrict__ projbf, float* __restrict__ out) {
  __shared__ bf16_t As[3 * 4096], Bs[3 * 4096];
  TILE_IDS
  const int m0 = blockIdx.y * 128, n0 = blockIdx.x * 128;
  f32x4 acc[4][4] = {};
  gemm_ring(Fbf + (size_t)m0 * DIM, DIM, Wpg + (size_t)n0 * DIM, DIM, DIM,
            As, Bs, acc, w, lane, qoff, mw, nw);
  if (n0 < 512) {
#pragma unroll
    for (int s = 0; s < 4; ++s)
#pragma unroll
      for (int t = 0; t < 4; ++t) {
        const int col = n0 + nw + t * 16 + cc;
        const float bv = b1[col];
#pragma unroll
        for (int r = 0; r < 4; ++r)
          projbf[(size_t)(m0 + mw + s * 16 + cr + r) * HID + col] = (bf16_t)(acc[s][t][r] + bv);
      }
  } else {
#pragma unroll
    for (int s = 0; s < 4; ++s)
#pragma unroll
      for (int t = 0; t < 4; ++t) {
        const int col = (n0 - 512) + nw + t * 16 + cc;
        const float bv = b2[col];
#pragma unroll
        for (int r = 0; r < 4; ++r)
          out[(size_t)(m0 + mw + s * 16 + cr + r) * HID + col] = acc[s][t][r] + bv;
      }
  }
}

// ---- S3: weight[b] = proj[b] @ F[b]^T ----------------------------------------
__global__ __launch_bounds__(256) void weight_mfma(
    const bf16_t* __restrict__ projbf, const bf16_t* __restrict__ Fbf,
    bf16_t* __restrict__ wbuf, int b0) {
  __shared__ bf16_t As[3 * 4096], Bs[3 * 4096];
  TILE_IDS
  const int b = b0 + blockIdx.z;
  const bf16_t* A  = projbf + (size_t)b * SEQ * DIM;
  const bf16_t* Bt = Fbf    + (size_t)b * SEQ * DIM;
  bf16_t* C = wbuf + (size_t)blockIdx.z * SEQ * SEQ;
  const int m0 = blockIdx.y * 128, n0 = blockIdx.x * 128;
  f32x4 acc[4][4] = {};
  gemm_ring(A + (size_t)m0 * DIM, DIM, Bt + (size_t)n0 * DIM, DIM, DIM,
            As, Bs, acc, w, lane, qoff, mw, nw);
#pragma unroll
  for (int s = 0; s < 4; ++s)
#pragma unroll
    for (int t = 0; t < 4; ++t)
#pragma unroll
      for (int r = 0; r < 4; ++r)
        C[(size_t)(m0 + mw + s * 16 + cr + r) * SEQ + n0 + nw + t * 16 + cc] = (bf16_t)acc[s][t][r];
}

// ---- S4: GacT[b][m][j] = ([W2a;W2c] @ F[b]^T)[m][j] * sm_j -------------------
__global__ __launch_bounds__(256) void gact_mfma(
    const bf16_t* __restrict__ W2ac, const bf16_t* __restrict__ Fbf,
    const int* __restrict__ smask, bf16_t* __restrict__ GacT) {
  __shared__ bf16_t As[3 * 4096], Bs[3 * 4096];
  TILE_IDS
  const int b = blockIdx.z;
  const bf16_t* Bt = Fbf + (size_t)b * SEQ * DIM;
  const int m0 = blockIdx.y * 128, n0 = blockIdx.x * 128;
  f32x4 acc[4][4] = {};
  gemm_ring(W2ac + (size_t)m0 * DIM, DIM, Bt + (size_t)n0 * DIM, DIM, DIM,
            As, Bs, acc, w, lane, qoff, mw, nw);
  bf16_t* C = GacT + (size_t)b * SEQ * SEQ;
#pragma unroll
  for (int s = 0; s < 4; ++s)
#pragma unroll
    for (int t = 0; t < 4; ++t) {
      const int j = n0 + nw + t * 16 + cc;
      const float smj = (float)smask[b * SEQ + j];
#pragma unroll
      for (int r = 0; r < 4; ++r)
        C[(size_t)(m0 + mw + s * 16 + cr + r) * SEQ + j] = (bf16_t)(acc[s][t][r] * smj);
    }
}

// ---- S5: tri — out += sp*(trilW @ GaT^T) + sf*(triuW @ GcT^T) ----------------
__global__ __launch_bounds__(256) void tri_mfma(
    const bf16_t* __restrict__ wbuf, const bf16_t* __restrict__ GacT,
    const float* __restrict__ scaleP, const float* __restrict__ scaleF,
    float* __restrict__ out, int b0) {
  __shared__ bf16_t As[3 * 4096], BPs[3 * 2048], BFs[3 * 2048];
  const int tid = threadIdx.x;
  const int w = tid >> 6, lane = tid & 63;
  const int fr = lane & 15, fk = (lane >> 4) * 8;
  const int qoff = swz8(fr, lane >> 4);
  const int mw = (w >> 1) * 64, nw2 = (w & 1) * 32;
  const int cr = (lane >> 4) * 4, cc = lane & 15;
  const int b = b0 + blockIdx.z;
  const bf16_t* A    = wbuf + (size_t)blockIdx.z * SEQ * SEQ;
  const bf16_t* GaTp = GacT + (size_t)b * SEQ * SEQ + (size_t)(blockIdx.x * 64) * SEQ;
  const bf16_t* GaTf = GaTp + (size_t)512 * SEQ;
  const int i0 = blockIdx.y * 128;
  f32x4 accP[4][2] = {}, accF[4][2] = {};
  const bf16_t* Arow = A + (size_t)i0 * SEQ;
  // prologue: tiles 0,1 (4 loads/thread each)
  stage<128>(Arow,      SEQ, As,        w, lane);
  stage<64>(GaTp,       SEQ, BPs,       w, lane);
  stage<64>(GaTf,       SEQ, BFs,       w, lane);
  stage<128>(Arow + 32, SEQ, As + 4096, w, lane);
  stage<64>(GaTp + 32,  SEQ, BPs + 2048, w, lane);
  stage<64>(GaTf + 32,  SEQ, BFs + 2048, w, lane);
  WAITCNT4();
  BAR();
  int cur = 0;
  const int NT = SEQ / 32;
  for (int kt = 0; kt < NT; ++kt) {
    const int j0 = kt * 32;
    if (kt + 2 < NT) {
      const int nx = (cur >= 1) ? cur - 1 : 2;
      const int jn = j0 + 64;
      stage<128>(Arow + jn, SEQ, As  + nx * 4096, w, lane);
      stage<64>(GaTp + jn,  SEQ, BPs + nx * 2048, w, lane);
      stage<64>(GaTf + jn,  SEQ, BFs + nx * 2048, w, lane);
    }
    const bool wP = (j0 < i0 + mw + 64);
    const bool wF = (j0 + 31 > i0 + mw);
    if (wP || wF) {
      const bf16_t* abase  = As  + cur * 4096 + (mw >> 4) * 512 + qoff;
      const bf16_t* bpbase = BPs + cur * 2048 + (nw2 >> 4) * 512 + qoff;
      const bf16_t* bfbase = BFs + cur * 2048 + (nw2 >> 4) * 512 + qoff;
      bf16x8 bP[2], bF[2];
#pragma unroll
      for (int t = 0; t < 2; ++t) {
        if (wP) bP[t] = *(const bf16x8*)&bpbase[t * 512];
        if (wF) bF[t] = *(const bf16x8*)&bfbase[t * 512];
      }
#pragma unroll
      for (int s = 0; s < 4; ++s) {
        const int rlo = i0 + mw + s * 16;
        const bool pAny = (j0 < rlo + 15), pFull = (j0 + 31 < rlo);
        const bool fAny = (j0 + 31 > rlo), fFull = (j0 > rlo + 15);
        if (!pAny && !fAny) continue;
        const bf16x8 a = *(const bf16x8*)&abase[s * 512];
        if (pFull) {
#pragma unroll
          for (int t = 0; t < 2; ++t)
            accP[s][t] = __builtin_amdgcn_mfma_f32_16x16x32_bf16(a, bP[t], accP[s][t], 0, 0, 0);
        } else if (pAny) {
          const int cut = (rlo + fr) - (j0 + fk);     // keep e < cut  (j < i)
          bf16x8 ap = a;
#pragma unroll
          for (int e = 0; e < 8; ++e) if (e >= cut) ap[e] = (bf16_t)0.f;
#pragma unroll
          for (int t = 0; t < 2; ++t)
            accP[s][t] = __builtin_amdgcn_mfma_f32_16x16x32_bf16(ap, bP[t], accP[s][t], 0, 0, 0);
        }
        if (fFull) {
#pragma unroll
          for (int t = 0; t < 2; ++t)
            accF[s][t] = __builtin_amdgcn_mfma_f32_16x16x32_bf16(a, bF[t], accF[s][t], 0, 0, 0);
        } else if (fAny) {
          const int cut = (rlo + fr) - (j0 + fk);     // keep e > cut  (j > i)
          bf16x8 af = a;
#pragma unroll
          for (int e = 0; e < 8; ++e) if (e <= cut) af[e] = (bf16_t)0.f;
#pragma unroll
          for (int t = 0; t < 2; ++t)
            accF[s][t] = __builtin_amdgcn_mfma_f32_16x16x32_bf16(af, bF[t], accF[s][t], 0, 0, 0);
        }
      }
    }
    if (kt + 1 < NT) {
      if (kt + 2 < NT) { WAITCNT4(); } else { WAITCNT0(); }
      BAR();
    }
    cur = (cur == 2) ? 0 : cur + 1;
  }
#pragma unroll
  for (int s = 0; s < 4; ++s)
#pragma unroll
    for (int r = 0; r < 4; ++r) {
      const int row = i0 + mw + s * 16 + cr + r;
      const float spv = scaleP[b * SEQ + row];
      const float sfv = scaleF[b * SEQ + row];
#pragma unroll
      for (int t = 0; t < 2; ++t) {
        const int col = blockIdx.x * 64 + nw2 + t * 16 + cc;
        const size_t oi = ((size_t)b * SEQ + row) * HID + col;
        out[oi] = accP[s][t][r] * spv + accF[s][t][r] * sfv + out[oi];  // Gb already in out
      }
    }
}

extern "C" void kernel_launch(void* const* d_in, const int* in_sizes, int n_in,
                              void* d_out, int out_size, void* d_ws, size_t ws_size,
                              hipStream_t stream) {
  const float* F  = (const float*)d_in[0];
  const int*   sm = (const int*)  d_in[1];
  const float* W1 = (const float*)d_in[2];
  const float* b1 = (const float*)d_in[3];
  const float* W2 = (const float*)d_in[4];
  const float* b2 = (const float*)d_in[5];
  float* out = (float*)d_out;

  char* ws = (char*)d_ws;
  size_t off = 0;
  auto take = [&](size_t bytes) -> void* {
    void* p = ws + off;
    off += (bytes + 255) & ~(size_t)255;
    return p;
  };
  bf16_t* Fbf    = (bf16_t*)take((size_t)BATCH * SEQ * DIM * 2);   // 8 MB
  bf16_t* projbf = (bf16_t*)take((size_t)BATCH * SEQ * HID * 2);   // 8 MB
  bf16_t* GacT   = (bf16_t*)take((size_t)BATCH * SEQ * SEQ * 2);   // 16 MB
  bf16_t* Wpg    = (bf16_t*)take((size_t)1024 * 512 * 2);          // 1 MB
  bf16_t* W2ac   = (bf16_t*)take((size_t)1024 * 512 * 2);          // 1 MB
  float*  scaleP = (float*) take((size_t)BATCH * SEQ * 4);
  float*  scaleF = (float*) take((size_t)BATCH * SEQ * 4);

  const size_t wbytes = (size_t)SEQ * SEQ * 2;
  int chunk = (ws_size > off) ? (int)((ws_size - off) / wbytes) : 1;
  if (chunk > BATCH) chunk = BATCH;
  if (chunk < 1) chunk = 1;
  bf16_t* wbuf = (bf16_t*)(ws + off);

  scales_kernel<<<dim3(BATCH), dim3(1024), 0, stream>>>(sm, scaleP, scaleF);
  cvt_kernel<<<dim3(BATCH * SEQ * DIM / 8 / 256), dim3(256), 0, stream>>>(F, Fbf, BATCH * SEQ * DIM / 8);
  prepw_kernel<<<dim3(512), dim3(256), 0, stream>>>(W1, W2, Wpg, W2ac);

  pg_mfma<<<dim3(1024 / 128, BATCH * SEQ / 128), dim3(256), 0, stream>>>(
      Fbf, Wpg, b1, b2, projbf, out);
  gact_mfma<<<dim3(SEQ / 128, SEQ / 128, BATCH), dim3(256), 0, stream>>>(
      W2ac, Fbf, sm, GacT);
  for (int b0 = 0; b0 < BATCH; b0 += chunk) {
    const int nb = (BATCH - b0 < chunk) ? (BATCH - b0) : chunk;
    weight_mfma<<<dim3(SEQ / 128, SEQ / 128, nb), dim3(256), 0, stream>>>(projbf, Fbf, wbuf, b0);
    tri_mfma<<<dim3(HID / 64, SEQ / 128, nb), dim3(256), 0, stream>>>(
        wbuf, GacT, scaleP, scaleF, out, b0);
  }
}

// Round 6
// 107.256 us; speedup vs baseline: 1.0813x; 1.0813x over previous
//
#include <hip/hip_runtime.h>

// PastFutureContext: B=8, N=1024, d=h=512 — bf16 MFMA, ring-3 counted-vmcnt,
// small tiles (Mx64, BK=32, 36KB LDS) for 4 blocks/CU / 16 waves/CU TLP.
// Math: out = sp_i*(trilW @ GaT^T) + sf_i*(triuW @ GcT^T) + Gb, where
//   W[b]    = proj[b] @ F[b]^T        (proj = F@W1^T + b1)
//   GacT[b] = [W2a;W2c] @ F[b]^T * sm_j
//   Gb      = F @ W2b^T + b2   — written straight into out (f32); tri does RMW.
// LDS swizzle (verified r5: conflicts=0): lane l stages global col-slot
// ((l&3)-(l>>3))&3; read slot q(r,c0)=(c0+(r>>1))&3.

constexpr int BATCH = 8;
constexpr int SEQ   = 1024;
constexpr int DIM   = 512;
constexpr int HID   = 512;

typedef __bf16 bf16_t;
typedef bf16_t bf16x8 __attribute__((ext_vector_type(8)));
typedef float  f32x4  __attribute__((ext_vector_type(4)));
typedef float  f4     __attribute__((ext_vector_type(4)));

typedef __attribute__((address_space(1))) void gv_t;
typedef __attribute__((address_space(3))) void lv_t;

__device__ __forceinline__ void gload16(const bf16_t* g, bf16_t* l) {
  __builtin_amdgcn_global_load_lds((gv_t*)g, (lv_t*)l, 16, 0, 0);
}

#define WAIT3() asm volatile("s_waitcnt vmcnt(3)" ::: "memory")
#define WAIT0() asm volatile("s_waitcnt vmcnt(0)" ::: "memory")
#define BAR()   { __builtin_amdgcn_s_barrier(); __builtin_amdgcn_sched_barrier(0); }

// Stage a [ROWS x 32] bf16 tile (row-major, ld elems) into LDS as ROWS/16
// chunks of 512 elems. Lane l lands at elem l*8 of its chunk (linear dest).
// Pre-swizzled global source; see header comment.
template <int ROWS>
__device__ __forceinline__ void stage(const bf16_t* g, int ld, bf16_t* lds,
                                      int w, int lane) {
  const int r0 = lane >> 2;
  const int kc = ((((lane & 3) - (lane >> 3)) & 3)) * 8;
#pragma unroll
  for (int i = 0; i < ROWS / 64; ++i) {
    const int s = w * (ROWS / 64) + i;
    gload16(g + (size_t)(s * 16 + r0) * ld + kc, lds + s * 512);
  }
}

// read-side swizzled elem offset within a 16-row chunk (row fr, global slot c0)
__device__ __forceinline__ int swz8(int fr, int c0) {
  return (((fr << 2) | ((c0 + (fr >> 1)) & 3)) << 3);
}

// ---- S0: parallel scales ----------------------------------------------------
__global__ __launch_bounds__(1024) void scales_kernel(
    const int* __restrict__ smask, float* __restrict__ sp, float* __restrict__ sf) {
  const int b = blockIdx.x, t = threadIdx.x;
  const int v = smask[b * SEQ + t];
  int x = v;
#pragma unroll
  for (int o = 1; o < 64; o <<= 1) {
    int y = __shfl_up(x, o, 64);
    if ((t & 63) >= o) x += y;
  }
  __shared__ int wsum[16], wpre[17];
  if ((t & 63) == 63) wsum[t >> 6] = x;
  __syncthreads();
  if (t == 0) { int c = 0; for (int w = 0; w < 16; ++w) { wpre[w] = c; c += wsum[w]; } wpre[16] = c; }
  __syncthreads();
  const int inc = x + wpre[t >> 6];
  const float P  = (float)(inc - v);
  const float Fu = (float)(wpre[16] - inc);
  sp[b * SEQ + t] = v ? 1.f / (P  + 1e-8f) : 0.f;
  sf[b * SEQ + t] = v ? 1.f / (Fu + 1e-8f) : 0.f;
}

// ---- S1a: F -> bf16 ----------------------------------------------------------
__global__ void cvt_kernel(const float* __restrict__ in, bf16_t* __restrict__ out, int n8) {
  const int i = blockIdx.x * blockDim.x + threadIdx.x;
  if (i >= n8) return;
  const f4* p = (const f4*)(in + (size_t)i * 8);
  f4 v0 = p[0], v1 = p[1];
  bf16x8 o;
  o[0] = (bf16_t)v0[0]; o[1] = (bf16_t)v0[1]; o[2] = (bf16_t)v0[2]; o[3] = (bf16_t)v0[3];
  o[4] = (bf16_t)v1[0]; o[5] = (bf16_t)v1[1]; o[6] = (bf16_t)v1[2]; o[7] = (bf16_t)v1[3];
  *(bf16x8*)(out + (size_t)i * 8) = o;
}

// ---- S1b: weights -> bf16, restacked ----------------------------------------
__global__ __launch_bounds__(256) void prepw_kernel(
    const float* __restrict__ W1, const float* __restrict__ W2,
    bf16_t* __restrict__ Wpg, bf16_t* __restrict__ W2ac) {
  const int idx = blockIdx.x * 256 + threadIdx.x;
  const int r = idx >> 6, c8 = (idx & 63) * 8;
  const float* src;
  bf16_t* dst;
  if (r < 512)        { src = W1 + (size_t)r * 512 + c8;                    dst = Wpg  + (size_t)r * 512 + c8; }
  else if (r < 1024)  { src = W2 + (size_t)(r - 512) * 1536 + 512 + c8;     dst = Wpg  + (size_t)r * 512 + c8; }
  else if (r < 1536)  { src = W2 + (size_t)(r - 1024) * 1536 + c8;          dst = W2ac + (size_t)(r - 1024) * 512 + c8; }
  else                { src = W2 + (size_t)(r - 1536) * 1536 + 1024 + c8;   dst = W2ac + (size_t)(r - 1024) * 512 + c8; }
  f4 v0 = *(const f4*)src, v1 = *(const f4*)(src + 4);
  bf16x8 o;
  o[0] = (bf16_t)v0[0]; o[1] = (bf16_t)v0[1]; o[2] = (bf16_t)v0[2]; o[3] = (bf16_t)v0[3];
  o[4] = (bf16_t)v1[0]; o[5] = (bf16_t)v1[1]; o[6] = (bf16_t)v1[2]; o[7] = (bf16_t)v1[3];
  *(bf16x8*)dst = o;
}

// ---- ring-3 counted-vmcnt 128x64 GEMM core (wave 64x32, acc 4x2) -------------
__device__ __forceinline__ void gemm_ring(
    const bf16_t* __restrict__ A, int lda, const bf16_t* __restrict__ Bt, int ldb,
    int K, bf16_t* As, bf16_t* Bs, f32x4 acc[4][2],
    int w, int lane, int qoff, int mw, int nw) {
  const int NT = K / 32;
  stage<128>(A,       lda, As,        w, lane);
  stage<64>(Bt,       ldb, Bs,        w, lane);
  stage<128>(A + 32,  lda, As + 4096, w, lane);
  stage<64>(Bt + 32,  ldb, Bs + 2048, w, lane);
  WAIT3();
  BAR();
  int cur = 0;
  for (int k = 0; k < NT; ++k) {
    if (k + 2 < NT) {
      const int nx = (cur >= 1) ? cur - 1 : 2;          // (cur+2)%3
      stage<128>(A  + (k + 2) * 32, lda, As + nx * 4096, w, lane);
      stage<64>(Bt + (k + 2) * 32, ldb, Bs + nx * 2048, w, lane);
    }
    const bf16_t* ab = As + cur * 4096 + (mw >> 4) * 512 + qoff;
    const bf16_t* bb = Bs + cur * 2048 + (nw >> 4) * 512 + qoff;
    bf16x8 a[4], b[2];
#pragma unroll
    for (int s = 0; s < 4; ++s) a[s] = *(const bf16x8*)&ab[s * 512];
#pragma unroll
    for (int t = 0; t < 2; ++t) b[t] = *(const bf16x8*)&bb[t * 512];
#pragma unroll
    for (int s = 0; s < 4; ++s)
#pragma unroll
      for (int t = 0; t < 2; ++t)
        acc[s][t] = __builtin_amdgcn_mfma_f32_16x16x32_bf16(a[s], b[t], acc[s][t], 0, 0, 0);
    if (k + 1 < NT) {
      if (k + 2 < NT) { WAIT3(); } else { WAIT0(); }
      BAR();
    }
    cur = (cur == 2) ? 0 : cur + 1;
  }
}

#define TILE_IDS                                  \
  const int tid = threadIdx.x;                    \
  const int w = tid >> 6, lane = tid & 63;        \
  const int fr = lane & 15;                       \
  const int qoff = swz8(fr, lane >> 4);           \
  const int mw = (w >> 1) * 64, nw = (w & 1) * 32;\
  const int cr = (lane >> 4) * 4, cc = lane & 15;

// ---- S2: [proj | Gb] = F @ [W1;W2b]^T + [b1;b2]; Gb straight into out --------
__global__ __launch_bounds__(256) void pg_mfma(
    const bf16_t* __restrict__ Fbf, const bf16_t* __restrict__ Wpg,
    const float* __restrict__ b1, const float* __restrict__ b2,
    bf16_t* __restrict__ projbf, float* __restrict__ out) {
  __shared__ bf16_t As[3 * 4096], Bs[3 * 2048];
  TILE_IDS
  const int m0 = blockIdx.y * 128, n0 = blockIdx.x * 64;
  f32x4 acc[4][2] = {};
  gemm_ring(Fbf + (size_t)m0 * DIM, DIM, Wpg + (size_t)n0 * DIM, DIM, DIM,
            As, Bs, acc, w, lane, qoff, mw, nw);
  if (n0 < 512) {
#pragma unroll
    for (int s = 0; s < 4; ++s)
#pragma unroll
      for (int t = 0; t < 2; ++t) {
        const int col = n0 + nw + t * 16 + cc;
        const float bv = b1[col];
#pragma unroll
        for (int r = 0; r < 4; ++r)
          projbf[(size_t)(m0 + mw + s * 16 + cr + r) * HID + col] = (bf16_t)(acc[s][t][r] + bv);
      }
  } else {
#pragma unroll
    for (int s = 0; s < 4; ++s)
#pragma unroll
      for (int t = 0; t < 2; ++t) {
        const int col = (n0 - 512) + nw + t * 16 + cc;
        const float bv = b2[col];
#pragma unroll
        for (int r = 0; r < 4; ++r)
          out[(size_t)(m0 + mw + s * 16 + cr + r) * HID + col] = acc[s][t][r] + bv;
      }
  }
}

// ---- S3: weight[b] = proj[b] @ F[b]^T ----------------------------------------
__global__ __launch_bounds__(256) void weight_mfma(
    const bf16_t* __restrict__ projbf, const bf16_t* __restrict__ Fbf,
    bf16_t* __restrict__ wbuf, int b0) {
  __shared__ bf16_t As[3 * 4096], Bs[3 * 2048];
  TILE_IDS
  const int b = b0 + blockIdx.z;
  const bf16_t* A  = projbf + (size_t)b * SEQ * DIM;
  const bf16_t* Bt = Fbf    + (size_t)b * SEQ * DIM;
  bf16_t* C = wbuf + (size_t)blockIdx.z * SEQ * SEQ;
  const int m0 = blockIdx.y * 128, n0 = blockIdx.x * 64;
  f32x4 acc[4][2] = {};
  gemm_ring(A + (size_t)m0 * DIM, DIM, Bt + (size_t)n0 * DIM, DIM, DIM,
            As, Bs, acc, w, lane, qoff, mw, nw);
#pragma unroll
  for (int s = 0; s < 4; ++s)
#pragma unroll
    for (int t = 0; t < 2; ++t)
#pragma unroll
      for (int r = 0; r < 4; ++r)
        C[(size_t)(m0 + mw + s * 16 + cr + r) * SEQ + n0 + nw + t * 16 + cc] = (bf16_t)acc[s][t][r];
}

// ---- S4: GacT[b][m][j] = ([W2a;W2c] @ F[b]^T)[m][j] * sm_j -------------------
__global__ __launch_bounds__(256) void gact_mfma(
    const bf16_t* __restrict__ W2ac, const bf16_t* __restrict__ Fbf,
    const int* __restrict__ smask, bf16_t* __restrict__ GacT) {
  __shared__ bf16_t As[3 * 4096], Bs[3 * 2048];
  TILE_IDS
  const int b = blockIdx.z;
  const bf16_t* Bt = Fbf + (size_t)b * SEQ * DIM;
  const int m0 = blockIdx.y * 128, n0 = blockIdx.x * 64;
  f32x4 acc[4][2] = {};
  gemm_ring(W2ac + (size_t)m0 * DIM, DIM, Bt + (size_t)n0 * DIM, DIM, DIM,
            As, Bs, acc, w, lane, qoff, mw, nw);
  bf16_t* C = GacT + (size_t)b * SEQ * SEQ;
#pragma unroll
  for (int s = 0; s < 4; ++s)
#pragma unroll
    for (int t = 0; t < 2; ++t) {
      const int j = n0 + nw + t * 16 + cc;
      const float smj = (float)smask[b * SEQ + j];
#pragma unroll
      for (int r = 0; r < 4; ++r)
        C[(size_t)(m0 + mw + s * 16 + cr + r) * SEQ + j] = (bf16_t)(acc[s][t][r] * smj);
    }
}

// ---- S5: tri — out += sp*(trilW @ GaT^T) + sf*(triuW @ GcT^T) ----------------
// block 64(i) x 64(n); waves 2x2 (32x32 each); acc 2x2 per triangle.
__global__ __launch_bounds__(256) void tri_mfma(
    const bf16_t* __restrict__ wbuf, const bf16_t* __restrict__ GacT,
    const float* __restrict__ scaleP, const float* __restrict__ scaleF,
    float* __restrict__ out, int b0) {
  __shared__ bf16_t As[3 * 2048], BPs[3 * 2048], BFs[3 * 2048];
  const int tid = threadIdx.x;
  const int w = tid >> 6, lane = tid & 63;
  const int fr = lane & 15, fk = (lane >> 4) * 8;
  const int qoff = swz8(fr, lane >> 4);
  const int mw = (w >> 1) * 32, nw2 = (w & 1) * 32;
  const int cr = (lane >> 4) * 4, cc = lane & 15;
  const int b = b0 + blockIdx.z;
  const bf16_t* A    = wbuf + (size_t)blockIdx.z * SEQ * SEQ;
  const bf16_t* GaTp = GacT + (size_t)b * SEQ * SEQ + (size_t)(blockIdx.x * 64) * SEQ;
  const bf16_t* GaTf = GaTp + (size_t)512 * SEQ;
  const int i0 = blockIdx.y * 64;
  f32x4 accP[2][2] = {}, accF[2][2] = {};
  const bf16_t* Arow = A + (size_t)i0 * SEQ;
  // prologue: tiles 0,1 (3 loads/lane each)
  stage<64>(Arow,      SEQ, As,         w, lane);
  stage<64>(GaTp,      SEQ, BPs,        w, lane);
  stage<64>(GaTf,      SEQ, BFs,        w, lane);
  stage<64>(Arow + 32, SEQ, As + 2048,  w, lane);
  stage<64>(GaTp + 32, SEQ, BPs + 2048, w, lane);
  stage<64>(GaTf + 32, SEQ, BFs + 2048, w, lane);
  WAIT3();
  BAR();
  int cur = 0;
  const int NT = SEQ / 32;
  for (int kt = 0; kt < NT; ++kt) {
    const int j0 = kt * 32;
    if (kt + 2 < NT) {
      const int nx = (cur >= 1) ? cur - 1 : 2;
      const int jn = j0 + 64;
      stage<64>(Arow + jn, SEQ, As  + nx * 2048, w, lane);
      stage<64>(GaTp + jn, SEQ, BPs + nx * 2048, w, lane);
      stage<64>(GaTf + jn, SEQ, BFs + nx * 2048, w, lane);
    }
    const bool wP = (j0 < i0 + mw + 31);      // any s has pAny
    const bool wF = (j0 + 31 > i0 + mw);      // any s has fAny
    if (wP || wF) {
      const bf16_t* abase  = As  + cur * 2048 + (mw >> 4) * 512 + qoff;
      const bf16_t* bpbase = BPs + cur * 2048 + (nw2 >> 4) * 512 + qoff;
      const bf16_t* bfbase = BFs + cur * 2048 + (nw2 >> 4) * 512 + qoff;
      bf16x8 bP[2], bF[2];
#pragma unroll
      for (int t = 0; t < 2; ++t) {
        if (wP) bP[t] = *(const bf16x8*)&bpbase[t * 512];
        if (wF) bF[t] = *(const bf16x8*)&bfbase[t * 512];
      }
#pragma unroll
      for (int s = 0; s < 2; ++s) {
        const int rlo = i0 + mw + s * 16;
        const bool pAny = (j0 < rlo + 15), pFull = (j0 + 31 < rlo);
        const bool fAny = (j0 + 31 > rlo), fFull = (j0 > rlo + 15);
        if (!pAny && !fAny) continue;
        const bf16x8 a = *(const bf16x8*)&abase[s * 512];
        if (pFull) {
#pragma unroll
          for (int t = 0; t < 2; ++t)
            accP[s][t] = __builtin_amdgcn_mfma_f32_16x16x32_bf16(a, bP[t], accP[s][t], 0, 0, 0);
        } else if (pAny) {
          const int cut = (rlo + fr) - (j0 + fk);     // keep e < cut  (j < i)
          bf16x8 ap = a;
#pragma unroll
          for (int e = 0; e < 8; ++e) if (e >= cut) ap[e] = (bf16_t)0.f;
#pragma unroll
          for (int t = 0; t < 2; ++t)
            accP[s][t] = __builtin_amdgcn_mfma_f32_16x16x32_bf16(ap, bP[t], accP[s][t], 0, 0, 0);
        }
        if (fFull) {
#pragma unroll
          for (int t = 0; t < 2; ++t)
            accF[s][t] = __builtin_amdgcn_mfma_f32_16x16x32_bf16(a, bF[t], accF[s][t], 0, 0, 0);
        } else if (fAny) {
          const int cut = (rlo + fr) - (j0 + fk);     // keep e > cut  (j > i)
          bf16x8 af = a;
#pragma unroll
          for (int e = 0; e < 8; ++e) if (e <= cut) af[e] = (bf16_t)0.f;
#pragma unroll
          for (int t = 0; t < 2; ++t)
            accF[s][t] = __builtin_amdgcn_mfma_f32_16x16x32_bf16(af, bF[t], accF[s][t], 0, 0, 0);
        }
      }
    }
    if (kt + 1 < NT) {
      if (kt + 2 < NT) { WAIT3(); } else { WAIT0(); }
      BAR();
    }
    cur = (cur == 2) ? 0 : cur + 1;
  }
#pragma unroll
  for (int s = 0; s < 2; ++s)
#pragma unroll
    for (int r = 0; r < 4; ++r) {
      const int row = i0 + mw + s * 16 + cr + r;
      const float spv = scaleP[b * SEQ + row];
      const float sfv = scaleF[b * SEQ + row];
#pragma unroll
      for (int t = 0; t < 2; ++t) {
        const int col = blockIdx.x * 64 + nw2 + t * 16 + cc;
        const size_t oi = ((size_t)b * SEQ + row) * HID + col;
        out[oi] = accP[s][t][r] * spv + accF[s][t][r] * sfv + out[oi];  // Gb already in out
      }
    }
}

extern "C" void kernel_launch(void* const* d_in, const int* in_sizes, int n_in,
                              void* d_out, int out_size, void* d_ws, size_t ws_size,
                              hipStream_t stream) {
  const float* F  = (const float*)d_in[0];
  const int*   sm = (const int*)  d_in[1];
  const float* W1 = (const float*)d_in[2];
  const float* b1 = (const float*)d_in[3];
  const float* W2 = (const float*)d_in[4];
  const float* b2 = (const float*)d_in[5];
  float* out = (float*)d_out;

  char* ws = (char*)d_ws;
  size_t off = 0;
  auto take = [&](size_t bytes) -> void* {
    void* p = ws + off;
    off += (bytes + 255) & ~(size_t)255;
    return p;
  };
  bf16_t* Fbf    = (bf16_t*)take((size_t)BATCH * SEQ * DIM * 2);   // 8 MB
  bf16_t* projbf = (bf16_t*)take((size_t)BATCH * SEQ * HID * 2);   // 8 MB
  bf16_t* GacT   = (bf16_t*)take((size_t)BATCH * SEQ * SEQ * 2);   // 16 MB
  bf16_t* Wpg    = (bf16_t*)take((size_t)1024 * 512 * 2);          // 1 MB
  bf16_t* W2ac   = (bf16_t*)take((size_t)1024 * 512 * 2);          // 1 MB
  float*  scaleP = (float*) take((size_t)BATCH * SEQ * 4);
  float*  scaleF = (float*) take((size_t)BATCH * SEQ * 4);

  const size_t wbytes = (size_t)SEQ * SEQ * 2;
  int chunk = (ws_size > off) ? (int)((ws_size - off) / wbytes) : 1;
  if (chunk > BATCH) chunk = BATCH;
  if (chunk < 1) chunk = 1;
  bf16_t* wbuf = (bf16_t*)(ws + off);

  scales_kernel<<<dim3(BATCH), dim3(1024), 0, stream>>>(sm, scaleP, scaleF);
  cvt_kernel<<<dim3(BATCH * SEQ * DIM / 8 / 256), dim3(256), 0, stream>>>(F, Fbf, BATCH * SEQ * DIM / 8);
  prepw_kernel<<<dim3(512), dim3(256), 0, stream>>>(W1, W2, Wpg, W2ac);

  pg_mfma<<<dim3(1024 / 64, BATCH * SEQ / 128), dim3(256), 0, stream>>>(
      Fbf, Wpg, b1, b2, projbf, out);
  gact_mfma<<<dim3(SEQ / 64, SEQ / 128, BATCH), dim3(256), 0, stream>>>(
      W2ac, Fbf, sm, GacT);
  for (int b0 = 0; b0 < BATCH; b0 += chunk) {
    const int nb = (BATCH - b0 < chunk) ? (BATCH - b0) : chunk;
    weight_mfma<<<dim3(SEQ / 64, SEQ / 128, nb), dim3(256), 0, stream>>>(projbf, Fbf, wbuf, b0);
    tri_mfma<<<dim3(HID / 64, SEQ / 64, nb), dim3(256), 0, stream>>>(
        wbuf, GacT, scaleP, scaleF, out, b0);
  }
}